// Round 6
// baseline (688.359 us; speedup 1.0000x reference)
//
#include <hip/hip_runtime.h>
#include <hip/hip_bf16.h>
#include <stdint.h>

typedef __bf16 bf16x8 __attribute__((ext_vector_type(8)));
typedef float f32x4 __attribute__((ext_vector_type(4)));
typedef unsigned short u16;
typedef u16 u16x8 __attribute__((ext_vector_type(8)));
typedef uint32_t u32x4 __attribute__((ext_vector_type(4)));

#define RES 512
#define C3 144
#define CPP 48
#define HID 256
#define TPB 128
#define K0 160
#define BK_PAD 264
#define PLANE_ELEMS ((size_t)RES * RES * CPP)
#define NPTS 524288
#define TILES 16
#define GRID (NPTS / (TPB * TILES))   // 256 blocks, 1 per CU
#define GTASKS (TPB * 18)             // 2304 gather tasks per tile
// fragment-major weight image (u16 offsets)
#define L0_U16 (HID * K0)        // 40960
#define L12_U16 (HID * HID)      // 65536
#define L1_IMG L0_U16
#define L2_IMG (L0_U16 + L12_U16)
#define WIMG_U16 (L0_U16 + 2 * L12_U16)

static __device__ __forceinline__ float bf2f(u16 u) {
    uint32_t x = ((uint32_t)u) << 16;
    union { uint32_t i; float f; } c; c.i = x; return c.f;
}
static __device__ __forceinline__ u16 f2bf(float f) {
    __bf16 h = (__bf16)f;
    return __builtin_bit_cast(u16, h);
}

// ---- preprocessing: (144,512,512) f32 -> 3 x [512][512][48] bf16 ----
__global__ __launch_bounds__(256) void k_transpose(const float* __restrict__ tri,
                                                   u16* __restrict__ planes) {
    int id = blockIdx.x * 256 + threadIdx.x;
    int p = id >> 18;
    int rem = id & ((1 << 18) - 1);
    int y = rem >> 9, x = rem & (RES - 1);
    const float* src = tri + ((size_t)p * CPP) * (RES * RES) + (size_t)y * RES + x;
    u16 outv[CPP] __attribute__((aligned(16)));
    #pragma unroll
    for (int c = 0; c < CPP; ++c)
        outv[c] = f2bf(src[(size_t)c * (RES * RES)]);
    u16* dst = planes + (size_t)id * CPP;
    #pragma unroll
    for (int j = 0; j < 6; ++j)
        ((u32x4*)dst)[j] = ((const u32x4*)outv)[j];
}

// ---- weights -> fragment-major bf16 image (identical to R0) ----
// L0 frag addr = ((w*5+kb)*2+mf)*512 + lane*8 + j   (kb 0..4)
// L1/L2      = ((w*8+kb)*2+mf)*512 + lane*8 + j     (kb 0..7)
// value = W[w*32 + mf*16 + (lane&15)][kb*32 + (lane>>4)*8 + j]
__global__ __launch_bounds__(256) void k_prep_w(const float* __restrict__ w0,
                                                const float* __restrict__ w1,
                                                const float* __restrict__ w2,
                                                u16* __restrict__ wimg) {
    int id = blockIdx.x * 256 + threadIdx.x;   // 65536 threads
    if (id < L0_U16) {
        int j = id & 7;
        int f = id >> 3;
        int lane = f & 63;
        int g2 = f >> 6;          // 0..79
        int mf = g2 & 1;
        int t2 = g2 >> 1;         // 0..39
        int kb = t2 % 5;
        int w  = t2 / 5;
        int m = w * 32 + mf * 16 + (lane & 15);
        int k = kb * 32 + (lane >> 4) * 8 + j;
        wimg[id] = f2bf(k < C3 ? w0[m * C3 + k] : 0.f);
    }
    {
        int j = id & 7;
        int f = id >> 3;
        int lane = f & 63;
        int g2 = f >> 6;          // 0..127
        int mf = g2 & 1;
        int t2 = g2 >> 1;         // 0..63
        int kb = t2 & 7;
        int w  = t2 >> 3;
        int m = w * 32 + mf * 16 + (lane & 15);
        int k = kb * 32 + (lane >> 4) * 8 + j;
        wimg[L1_IMG + id] = f2bf(w1[m * HID + k]);
        wimg[L2_IMG + id] = f2bf(w2[m * HID + k]);
    }
}

// ---- R0 kbloop: pure m-split, wave owns 32 m-rows x all 128 points ----
template<int NKB>
static __device__ __forceinline__ void do_kbloop(
    const u16* __restrict__ wl, const u16* buf, f32x4 (&acc)[2][8],
    int wave, int lane)
{
    const int r = lane & 15;
    const int g = lane >> 4;
    #pragma unroll
    for (int kb = 0; kb < NKB; ++kb) {
        bf16x8 a[2];
        #pragma unroll
        for (int mf = 0; mf < 2; ++mf)
            a[mf] = *(const bf16x8*)(wl + ((size_t)((wave * NKB + kb) * 2 + mf)) * 512 + lane * 8);
        #pragma unroll
        for (int h = 0; h < 2; ++h) {
            bf16x8 b[4];
            #pragma unroll
            for (int nf = 0; nf < 4; ++nf)
                b[nf] = *(const bf16x8*)(buf + ((h * 4 + nf) * 16 + r) * BK_PAD + kb * 32 + g * 8);
            #pragma unroll
            for (int mf = 0; mf < 2; ++mf)
                #pragma unroll
                for (int nf = 0; nf < 4; ++nf)
                    acc[mf][h * 4 + nf] = __builtin_amdgcn_mfma_f32_16x16x32_bf16(
                        a[mf], b[nf], acc[mf][h * 4 + nf], 0, 0, 0);
        }
    }
}

static __device__ __forceinline__ void epilogue(
    f32x4 (&acc)[2][8], const float* __restrict__ bias,
    u16* buf, int wave, int lane)
{
    const int r = lane & 15;
    const int g = lane >> 4;
    #pragma unroll
    for (int mf = 0; mf < 2; ++mf) {
        int mb = wave * 32 + mf * 16 + g * 4;
        f32x4 bb = *(const f32x4*)(bias + mb);
        #pragma unroll
        for (int nf = 0; nf < 8; ++nf) {
            int n = nf * 16 + r;
            union { u16 u[4]; unsigned long long v; } pk;
            #pragma unroll
            for (int q = 0; q < 4; ++q) {
                float v = acc[mf][nf][q] + bb[q];
                pk.u[q] = f2bf(v > 0.0f ? v : 0.0f);
            }
            *(unsigned long long*)(buf + n * BK_PAD + mb) = pk.v;
        }
    }
}

// ---- gather prefetch: issue (loads -> regs) / resolve (lerp -> LDS) ----
// Coords are self-computed per task (no LDS tables, no barrier needed).
static __device__ __forceinline__ void gather_issue(
    const float* __restrict__ points, const u16* __restrict__ planes,
    int p0n, int t,
    float (&hix)[5], float (&hiy)[5],
    u16x8 (&hc0)[5], u16x8 (&hc1)[5], u16x8 (&hc2)[5], u16x8 (&hc3)[5])
{
    #pragma unroll
    for (int rr = 0; rr < 5; ++rr) {
        int task = rr * 512 + t;
        if (task < GTASKS) {
            int pt = task / 18;
            int rem = task - pt * 18;
            int pi = rem / 6;
            int ch = rem - pi * 6;
            const float* pp = points + (size_t)(p0n + pt) * 3;
            float px = pp[0] * 2.f - 1.f;
            float py = pp[1] * 2.f - 1.f;
            float pz = pp[2] * 2.f - 1.f;
            float gx = (pi == 1) ? py : px;     // pi0:(px,py) pi1:(py,pz) pi2:(px,pz)
            float gy = (pi == 0) ? py : pz;
            float ix = (gx + 1.f) * 0.5f * (float)(RES - 1);
            float iy = (gy + 1.f) * 0.5f * (float)(RES - 1);
            hix[rr] = ix; hiy[rr] = iy;
            float fx = floorf(ix), fy = floorf(iy);
            int x0 = ::min(::max((int)fx, 0), RES - 1);
            int x1 = ::min(::max((int)fx + 1, 0), RES - 1);
            int y0 = ::min(::max((int)fy, 0), RES - 1);
            int y1 = ::min(::max((int)fy + 1, 0), RES - 1);
            const u16* pl = planes + (size_t)pi * PLANE_ELEMS + ch * 8;
            hc0[rr] = *(const u16x8*)(pl + (uint32_t)(y0 * RES + x0) * CPP);
            hc1[rr] = *(const u16x8*)(pl + (uint32_t)(y0 * RES + x1) * CPP);
            hc2[rr] = *(const u16x8*)(pl + (uint32_t)(y1 * RES + x0) * CPP);
            hc3[rr] = *(const u16x8*)(pl + (uint32_t)(y1 * RES + x1) * CPP);
        }
    }
}

static __device__ __forceinline__ void gather_resolve(
    u16* __restrict__ bn, int t,
    const float (&hix)[5], const float (&hiy)[5],
    const u16x8 (&hc0)[5], const u16x8 (&hc1)[5],
    const u16x8 (&hc2)[5], const u16x8 (&hc3)[5])
{
    if (t < TPB) {   // zero K-pad cols [144,160) of the next buffer
        u32x4 z = {0, 0, 0, 0};
        *(u32x4*)&bn[t * BK_PAD + 144] = z;
        *(u32x4*)&bn[t * BK_PAD + 152] = z;
    }
    #pragma unroll
    for (int rr = 0; rr < 5; ++rr) {
        int task = rr * 512 + t;
        if (task < GTASKS) {
            int pt = task / 18;
            int rem = task - pt * 18;
            int pi = rem / 6;
            int ch = rem - pi * 6;
            float ix = hix[rr], iy = hiy[rr];
            float wx1 = ix - floorf(ix);
            float wy1 = iy - floorf(iy);
            float W0 = (1.f - wy1) * (1.f - wx1);
            float W1 = (1.f - wy1) * wx1;
            float W2 = wy1 * (1.f - wx1);
            float W3 = wy1 * wx1;
            u16x8 v0 = hc0[rr], v1 = hc1[rr], v2 = hc2[rr], v3 = hc3[rr];
            u16x8 res;
            #pragma unroll
            for (int j = 0; j < 8; ++j) {
                float v = W0 * bf2f(v0[j]) + W1 * bf2f(v1[j])
                        + W2 * bf2f(v2[j]) + W3 * bf2f(v3[j]);
                res[j] = f2bf(v);
            }
            *(u16x8*)&bn[pt * BK_PAD + pi * CPP + ch * 8] = res;
        }
    }
}

// Pipelined persistent kernel: 256 blocks (1/CU), 512 threads (8 waves,
// pure m-split), 16 tiles of 128 pts each, double-buffered LDS.
// Tile i+1's gather loads are issued before tile i's L0 kbloop and
// resolved right after its first barrier -> gather latency hides under MFMA.
__global__ __launch_bounds__(512)
__attribute__((amdgpu_waves_per_eu(2, 2)))
void k_fused(
    const float* __restrict__ points,
    const u16* __restrict__ planes,
    const u16* __restrict__ wimg,
    const float* __restrict__ b0, const float* __restrict__ b1,
    const float* __restrict__ b2,
    const float* __restrict__ wa, const float* __restrict__ ba,
    float* __restrict__ outp)
{
    __shared__ u16 buf[2][TPB * BK_PAD];       // 135168 B
    __shared__ float part[8 * TPB];            // 4096 B (alpha partials)
    const int t = threadIdx.x;
    const int lane = t & 63;
    const int wave = t >> 6;
    const int r = lane & 15;
    const int g = lane >> 4;
    const int tile0 = blockIdx.x * TILES;

    float hix[5], hiy[5];
    u16x8 hc0[5], hc1[5], hc2[5], hc3[5];

    // ---- prologue: gather tile 0 into buf[0] (latency exposed once) ----
    gather_issue(points, planes, tile0 * TPB, t, hix, hiy, hc0, hc1, hc2, hc3);
    gather_resolve(&buf[0][0], t, hix, hiy, hc0, hc1, hc2, hc3);
    __syncthreads();

    int cur = 0;
    for (int it = 0; it < TILES; ++it) {
        const u16* bc = &buf[cur][0];
        u16* bn = &buf[cur ^ 1][0];
        const int p0 = (tile0 + it) * TPB;
        const bool pref = (it + 1 < TILES);

        // issue next tile's gather loads (held in regs through L0)
        if (pref)
            gather_issue(points, planes, p0 + TPB, t, hix, hiy, hc0, hc1, hc2, hc3);

        // ---- layer 0: feats -> act0 (in place in bc) ----
        {
            f32x4 acc[2][8] = {{}};
            do_kbloop<5>(wimg, bc, acc, wave, lane);
            __syncthreads();                       // S3 (drains gather loads)
            epilogue(acc, b0, (u16*)bc, wave, lane);
            if (pref)
                gather_resolve(bn, t, hix, hiy, hc0, hc1, hc2, hc3);
            __syncthreads();                       // S4
        }
        // ---- layer 1 ----
        {
            f32x4 acc[2][8] = {{}};
            do_kbloop<8>(wimg + L1_IMG, bc, acc, wave, lane);
            __syncthreads();                       // S5
            epilogue(acc, b1, (u16*)bc, wave, lane);
            __syncthreads();                       // S6
        }
        // ---- layer 2 + fused alpha ----
        {
            f32x4 acc[2][8] = {{}};
            do_kbloop<8>(wimg + L2_IMG, bc, acc, wave, lane);
            float pa[8];
            #pragma unroll
            for (int nf = 0; nf < 8; ++nf) pa[nf] = 0.f;
            #pragma unroll
            for (int mf = 0; mf < 2; ++mf) {
                int mb = wave * 32 + mf * 16 + g * 4;
                f32x4 bb = *(const f32x4*)(b2 + mb);
                f32x4 wv = *(const f32x4*)(wa + mb);
                #pragma unroll
                for (int nf = 0; nf < 8; ++nf) {
                    #pragma unroll
                    for (int q = 0; q < 4; ++q) {
                        float v = acc[mf][nf][q] + bb[q];
                        pa[nf] += wv[q] * (v > 0.f ? v : 0.f);
                    }
                }
            }
            #pragma unroll
            for (int nf = 0; nf < 8; ++nf) {
                pa[nf] += __shfl_xor(pa[nf], 16, 64);
                pa[nf] += __shfl_xor(pa[nf], 32, 64);
            }
            if (g == 0) {
                #pragma unroll
                for (int nf = 0; nf < 8; ++nf)
                    part[wave * TPB + nf * 16 + r] = pa[nf];
            }
            __syncthreads();                       // S7
            if (t < TPB) {
                float s = ba[0];
                #pragma unroll
                for (int w = 0; w < 8; ++w) s += part[w * TPB + t];
                outp[p0 + t] = s;
            }
            __syncthreads();                       // S8 (part reuse + buf swap)
        }
        cur ^= 1;
    }
}

extern "C" void kernel_launch(void* const* d_in, const int* in_sizes, int n_in,
                              void* d_out, int out_size, void* d_ws, size_t ws_size,
                              hipStream_t stream) {
    const float* points = (const float*)d_in[0];
    const float* tri    = (const float*)d_in[1];
    const float* w0 = (const float*)d_in[2];
    const float* b0 = (const float*)d_in[3];
    const float* w1 = (const float*)d_in[4];
    const float* b1 = (const float*)d_in[5];
    const float* w2 = (const float*)d_in[6];
    const float* b2 = (const float*)d_in[7];
    const float* wa = (const float*)d_in[8];
    const float* ba = (const float*)d_in[9];
    float* outp = (float*)d_out;

    char* wsb = (char*)d_ws;
    u16* planes = (u16*)wsb;                          // 75,497,472 B
    size_t off = 3 * PLANE_ELEMS * 2;
    u16* wimg = (u16*)(wsb + off);                    // 344,064 B

    k_transpose<<<(3 * RES * RES) / 256, 256, 0, stream>>>(tri, planes);
    k_prep_w<<<256, 256, 0, stream>>>(w0, w1, w2, wimg);
    k_fused<<<GRID, 512, 0, stream>>>(points, planes, wimg,
                                      b0, b1, b2, wa, ba, outp);
}